// Round 12
// baseline (205.390 us; speedup 1.0000x reference)
//
#include <hip/hip_runtime.h>
#include <math.h>

#define NUM_HEADS 8
#define NUM_GROUPS 32
#define EPS 1e-5f

constexpr int B  = 16;
constexpr int C  = 512;
constexpr int HW = 1024;   // 32*32
constexpr int HD = 64;

typedef short bf16x8 __attribute__((ext_vector_type(8)));
typedef float f32x4  __attribute__((ext_vector_type(4)));

#define QSCALE 0.1803368801111f  /* 0.125 * log2(e): softmax done in exp2 space */

__device__ inline unsigned short f2bf(float f) {
    union { float f; unsigned int u; } v; v.f = f;
    unsigned int r = (v.u + 0x7FFFu + ((v.u >> 16) & 1u)) >> 16;
    return (unsigned short)r;
}

// pack two fp32 -> bf16 pair by truncation, single v_perm_b32
__device__ __forceinline__ unsigned int pack_trunc(float lo, float hi) {
    return __builtin_amdgcn_perm(__float_as_uint(hi), __float_as_uint(lo), 0x07060302u);
}

// raw hardware exp2: inputs bounded, OCML subnormal wrapper is dead weight.
__device__ __forceinline__ float exp2_raw(float x) {
#if __has_builtin(__builtin_amdgcn_exp2f)
    return __builtin_amdgcn_exp2f(x);
#else
    float r; asm("v_exp_f32 %0, %1" : "=v"(r) : "v"(x)); return r;
#endif
}

// async global->LDS, 16B per lane. LDS dest = wave-uniform base + lane*16.
__device__ __forceinline__ void gld_lds16(void* lds, const void* g) {
    __builtin_amdgcn_global_load_lds(
        (const __attribute__((address_space(1))) void*)g,
        (__attribute__((address_space(3))) void*)lds, 16, 0, 0);
}

// gfx950 permlane swaps. pl32: dst lanes 32..63 <-> src lanes 0..31.
// pl16: dst lanes 16..31 <-> src lanes 0..15, dst 48..63 <-> src 32..47.
__device__ __forceinline__ void pl32_swap(unsigned int& a, unsigned int& b) {
#if __has_builtin(__builtin_amdgcn_permlane32_swap)
    auto r = __builtin_amdgcn_permlane32_swap(a, b, false, false);
    a = r[0]; b = r[1];
#else
    asm volatile("v_permlane32_swap_b32 %0, %1" : "+v"(a), "+v"(b));
#endif
}
__device__ __forceinline__ void pl16_swap(unsigned int& a, unsigned int& b) {
#if __has_builtin(__builtin_amdgcn_permlane16_swap)
    auto r = __builtin_amdgcn_permlane16_swap(a, b, false, false);
    a = r[0]; b = r[1];
#else
    asm volatile("v_permlane16_swap_b32 %0, %1" : "+v"(a), "+v"(b));
#endif
}

// Counted-vmcnt barrier (T3/T4): wait for all but VM outstanding VMEM ops,
// then raw s_barrier. NEVER drains to 0 in the main loop.
#define ABAR(VM) do {                                                   \
    asm volatile("s_waitcnt vmcnt(" VM ")\n\ts_barrier" ::: "memory");  \
    __builtin_amdgcn_sched_barrier(0);                                  \
} while (0)

// ---------------------------------------------------------------------------
// Kernel 1 (fused): blocks [0,512): GroupNorm -> xnT bf16 [b][t][c];
// blocks [512,1536): weight conversion fp32 -> bf16.
// ---------------------------------------------------------------------------
__global__ __launch_bounds__(256)
void fused_pre_kernel(const float* __restrict__ x,
                      const float* __restrict__ gamma,
                      const float* __restrict__ beta,
                      unsigned short* __restrict__ xnT,
                      const float* __restrict__ qkv_w,
                      const float* __restrict__ proj_w,
                      unsigned short* __restrict__ wqb) {
    if (blockIdx.x >= 512) {
        // ---- weight conversion ----
        const int i = (blockIdx.x - 512) * 256 + threadIdx.x;   // float4 index
        const int n1 = 786432 / 4;
        const int nt = 1048576 / 4;
        if (i >= nt) return;
        const float4 v = (i < n1) ? ((const float4*)qkv_w)[i]
                                  : ((const float4*)proj_w)[i - n1];
        ushort4 r;
        r.x = f2bf(v.x); r.y = f2bf(v.y); r.z = f2bf(v.z); r.w = f2bf(v.w);
        ((ushort4*)wqb)[i] = r;
        return;
    }
    // ---- GroupNorm ----
    const int bg = blockIdx.x;
    const int b = bg >> 5, g = bg & 31;
    const size_t base = ((size_t)b * C + (size_t)g * 16) * HW;

    float v[4][16];
    float sum = 0.f, sumsq = 0.f;
    #pragma unroll
    for (int p = 0; p < 4; ++p) {
        const int t = threadIdx.x + p * 256;
        #pragma unroll
        for (int cl = 0; cl < 16; ++cl) {
            const float f = x[base + (size_t)cl * HW + t];
            v[p][cl] = f;
            sum += f;
            sumsq += f * f;
        }
    }
    #pragma unroll
    for (int off = 32; off > 0; off >>= 1) {
        sum   += __shfl_down(sum, off, 64);
        sumsq += __shfl_down(sumsq, off, 64);
    }
    __shared__ float s_sum[4], s_sq[4];
    const int wid = threadIdx.x >> 6, lane = threadIdx.x & 63;
    if (lane == 0) { s_sum[wid] = sum; s_sq[wid] = sumsq; }
    __syncthreads();
    const float tsum = s_sum[0] + s_sum[1] + s_sum[2] + s_sum[3];
    const float tsq  = s_sq[0] + s_sq[1] + s_sq[2] + s_sq[3];
    const float mean = tsum * (1.0f / 16384.f);
    const float var  = tsq * (1.0f / 16384.f) - mean * mean;
    const float rstd = rsqrtf(var + EPS);

    float ga[16], be[16];
    #pragma unroll
    for (int cl = 0; cl < 16; ++cl) {
        ga[cl] = gamma[g * 16 + cl] * rstd;
        be[cl] = beta[g * 16 + cl] - mean * ga[cl];
    }

    #pragma unroll
    for (int p = 0; p < 4; ++p) {
        const int t = threadIdx.x + p * 256;
        unsigned short pk[16];
        #pragma unroll
        for (int cl = 0; cl < 16; ++cl)
            pk[cl] = f2bf(v[p][cl] * ga[cl] + be[cl]);
        unsigned short* dst = xnT + ((size_t)(b * 1024 + t)) * 512 + g * 16;
        *(uint4*)dst = *(const uint4*)pk;
        *(uint4*)(dst + 8) = *(const uint4*)(pk + 8);
    }
}

// ---------------------------------------------------------------------------
// MFMA GEMM core: T3/T4 pipeline (HW-verified round-6). Triple-buffered LDS
// (48 KB), counted-vmcnt raw barriers, drain to 0 only before the final step.
// ---------------------------------------------------------------------------
__device__ __forceinline__ void gemm_stage(const char* __restrict__ Ab,
                                           const char* __restrict__ Bb,
                                           int step, unsigned short* As,
                                           unsigned short* Bs,
                                           int w, int lrow, int lkc) {
    #pragma unroll
    for (int i = 0; i < 2; ++i) {
        const int row = w * 32 + i * 16 + lrow;
        const int kc = lkc ^ ((row >> 1) & 3);   // swizzle k-chunk
        const size_t goff = (size_t)row * 1024 + (size_t)step * 64 + kc * 16;
        gld_lds16((char*)As + w * 2048 + i * 1024, Ab + goff);
        gld_lds16((char*)Bs + w * 2048 + i * 1024, Bb + goff);
    }
}

__device__ __forceinline__ void gemm_step(const unsigned short* __restrict__ As,
                                          const unsigned short* __restrict__ Bs,
                                          f32x4 acc[4][4],
                                          int lo, int q4, int wm, int wn) {
    bf16x8 af[4], bfr[4];
    #pragma unroll
    for (int i = 0; i < 4; ++i) {
        const int ra = wm * 64 + i * 16 + lo;
        af[i]  = *(const bf16x8*)(As + ra * 32 + (q4 ^ ((ra >> 1) & 3)) * 8);
        const int rb = wn * 64 + i * 16 + lo;
        bfr[i] = *(const bf16x8*)(Bs + rb * 32 + (q4 ^ ((rb >> 1) & 3)) * 8);
    }
    __builtin_amdgcn_s_setprio(1);
    #pragma unroll
    for (int mi = 0; mi < 4; ++mi)
        #pragma unroll
        for (int ni = 0; ni < 4; ++ni)
            acc[mi][ni] = __builtin_amdgcn_mfma_f32_16x16x32_bf16(
                af[mi], bfr[ni], acc[mi][ni], 0, 0, 0);
    __builtin_amdgcn_s_setprio(0);
}

__device__ __forceinline__ void mfma_gemm_pipe(const char* __restrict__ Ab,
                                               const char* __restrict__ Bb,
                                               unsigned short* S,   // 3*8192 shorts
                                               f32x4 acc[4][4]) {
    const int tid = threadIdx.x;
    const int w = tid >> 6, lane = tid & 63;
    const int lo = lane & 15, q4 = lane >> 4;
    const int wm = w >> 1, wn = w & 1;
    const int lrow = lane >> 2, lkc = lane & 3;

    unsigned short* A0 = S;             unsigned short* B0 = S + 4096;
    unsigned short* A1 = S + 8192;      unsigned short* B1 = S + 12288;
    unsigned short* A2 = S + 16384;     unsigned short* B2 = S + 20480;

    gemm_stage(Ab, Bb, 0, A0, B0, w, lrow, lkc);
    gemm_stage(Ab, Bb, 1, A1, B1, w, lrow, lkc);
    ABAR("4");                                      // step 0 landed
    gemm_stage(Ab, Bb, 2, A2, B2, w, lrow, lkc);
    gemm_step(A0, B0, acc, lo, q4, wm, wn);

    #pragma unroll 1
    for (int ii = 0; ii < 4; ++ii) {
        const int i = 3 * ii + 1;
        ABAR("4");
        gemm_stage(Ab, Bb, i + 2, A0, B0, w, lrow, lkc);
        gemm_step(A1, B1, acc, lo, q4, wm, wn);
        ABAR("4");
        gemm_stage(Ab, Bb, i + 3, A1, B1, w, lrow, lkc);
        gemm_step(A2, B2, acc, lo, q4, wm, wn);
        ABAR("4");
        gemm_stage(Ab, Bb, i + 4, A2, B2, w, lrow, lkc);
        gemm_step(A0, B0, acc, lo, q4, wm, wn);
    }

    ABAR("4");
    gemm_stage(Ab, Bb, 15, A0, B0, w, lrow, lkc);
    gemm_step(A1, B1, acc, lo, q4, wm, wn);
    ABAR("4");
    gemm_step(A2, B2, acc, lo, q4, wm, wn);
    ABAR("0");
    gemm_step(A0, B0, acc, lo, q4, wm, wn);
}

// ---------------------------------------------------------------------------
// Kernel 3: QKV projection GEMM. 1D grid + bijective XCD remap (T1).
// ---------------------------------------------------------------------------
__global__ __launch_bounds__(256)
void qkv_mfma_kernel(const unsigned short* __restrict__ wqb,
                     const unsigned short* __restrict__ xnT,
                     const float* __restrict__ qkv_b,
                     unsigned short* __restrict__ Qt,
                     unsigned short* __restrict__ Kt,
                     unsigned short* __restrict__ Vb) {
    __shared__ __align__(16) unsigned short SMEM[3 * 8192];  // 48 KB pipeline; reused by V epilogue
    const int hw_id = blockIdx.x;
    const int wk = (hw_id % 192) * 8 + hw_id / 192;   // bijective, 1536 = 8*192
    const int bx = wk & 7;            // nBase index
    const int by = (wk >> 3) % 12;    // mBase index
    const int batch = wk / 96;
    const int mBase = by * 128, nBase = bx * 128;

    f32x4 acc[4][4] = {};
    mfma_gemm_pipe((const char*)(wqb + (size_t)mBase * 512),
                   (const char*)(xnT + ((size_t)batch * 1024 + nBase) * 512),
                   SMEM, acc);

    const int tid = threadIdx.x;
    const int w = tid >> 6, lane = tid & 63;
    const int lo = lane & 15, q4 = lane >> 4;
    const int wm = w >> 1, wn = w & 1;
    const int mw = mBase + wm * 64;          // head-aligned 64-row chunk
    const int tb = nBase + wn * 64;

    __syncthreads();   // all waves done with GEMM LDS

    if (mw < 1024) {
        const bool isQ = mw < 512;
        const int head = (mw >> 6) & 7;
        unsigned short* dst = (isQ ? Qt : Kt) + (((size_t)batch * 8 + head) << 16);
        const float sc = isQ ? QSCALE : 1.0f;
        #pragma unroll
        for (int mi = 0; mi < 4; ++mi) {
            const float4 bq = *(const float4*)(qkv_b + mw + mi * 16 + q4 * 4);
            #pragma unroll
            for (int ni = 0; ni < 4; ++ni) {
                const int t = tb + ni * 16 + lo;
                ushort4 pk;
                pk.x = f2bf((acc[mi][ni][0] + bq.x) * sc);
                pk.y = f2bf((acc[mi][ni][1] + bq.y) * sc);
                pk.z = f2bf((acc[mi][ni][2] + bq.z) * sc);
                pk.w = f2bf((acc[mi][ni][3] + bq.w) * sc);
                *(ushort4*)(dst + (size_t)t * 64 + mi * 16 + q4 * 4) = pk;
            }
        }
    } else {
        // V: LDS transpose -> coalesced uint4 stores into Vb[b][d][t].
        unsigned short* T = SMEM + w * 2048;         // 32 x 64 shorts
        unsigned short* Vrow = Vb + (size_t)batch * 524288 + (size_t)(mw - 1024) * 1024 + tb;
        const int rl8 = lane >> 3, c8 = lane & 7;
        #pragma unroll
        for (int p = 0; p < 2; ++p) {
            #pragma unroll
            for (int mi2 = 0; mi2 < 2; ++mi2) {
                const int mi = 2 * p + mi2;
                const float4 bq = *(const float4*)(qkv_b + mw + mi * 16 + q4 * 4);
                const int dl = mi2 * 16 + q4 * 4;
                #pragma unroll
                for (int ni = 0; ni < 4; ++ni) {
                    const int tl = ni * 16 + lo;
                    T[(dl + 0) * 64 + tl] = f2bf(acc[mi][ni][0] + bq.x);
                    T[(dl + 1) * 64 + tl] = f2bf(acc[mi][ni][1] + bq.y);
                    T[(dl + 2) * 64 + tl] = f2bf(acc[mi][ni][2] + bq.z);
                    T[(dl + 3) * 64 + tl] = f2bf(acc[mi][ni][3] + bq.w);
                }
            }
            #pragma unroll
            for (int i = 0; i < 4; ++i) {
                const int dl = i * 8 + rl8;
                const uint4 val = *(const uint4*)&T[dl * 64 + c8 * 8];
                *(uint4*)(Vrow + (size_t)(p * 32 + dl) * 1024 + c8 * 8) = val;
            }
        }
    }
}

// ---------------------------------------------------------------------------
// Attn helpers (round-4 verified): stage one 64-s K/V chunk; compute one chunk.
// Round-12 addition: l-sum via MFMA ones-contraction — lacc[nt] accumulates
// l[t] = sum_s exp2(S[s][t]) on the MFMA pipe (2 mfma/nt/chunk against the
// already-built PV B-operand bp), replacing ~26 VALU adds/chunk + the
// epilogue shfl reduce. All-ones A-frag is layout-independent; D col = lo = t,
// all rows identical. bp[nt][0] contracts s 0..31, bp[nt][1] s 32..63 (same
// k-slot coverage as the PV v0/v1 pair).
// ---------------------------------------------------------------------------
__device__ __forceinline__ void attn_stage(const unsigned short* __restrict__ Kp,
                                           const unsigned short* __restrict__ Vp,
                                           int s0, unsigned short* Kd,
                                           unsigned short* Vd,
                                           int w, int rl, int p8) {
    #pragma unroll
    for (int cc = 0; cc < 2; ++cc) {
        const int r = 16 * w + 8 * cc + rl;
        const int jj = p8 ^ (r & 7);
        gld_lds16(Kd + (16 * w + 8 * cc) * 64, Kp + (size_t)(s0 + r) * 64 + jj * 8);
        gld_lds16(Vd + (16 * w + 8 * cc) * 64, Vp + (size_t)r * 1024 + s0 + jj * 8);
    }
}

__device__ __forceinline__ void attn_chunk(const unsigned short* __restrict__ Kc,
                                           const unsigned short* __restrict__ Vc,
                                           const bf16x8 (&qf)[2][2],
                                           const bf16x8 ones,
                                           f32x4 (&oacc)[4][2], f32x4 (&lacc)[2],
                                           int lo, int q4, int xr) {
    // ---- S^T = K^T Q : sacc[mt][nt], D row s_local = 4*q4+reg, col t = lo
    f32x4 sacc[4][2] = {};
    __builtin_amdgcn_s_setprio(1);
    #pragma unroll
    for (int mt = 0; mt < 4; ++mt) {
        const unsigned short* kr = Kc + (16 * mt + lo) * 64;
        const bf16x8 a0 = *(const bf16x8*)(kr + ((q4    ) ^ xr) * 8);
        const bf16x8 a1 = *(const bf16x8*)(kr + ((q4 + 4) ^ xr) * 8);
        #pragma unroll
        for (int nt = 0; nt < 2; ++nt) {
            sacc[mt][nt] = __builtin_amdgcn_mfma_f32_16x16x32_bf16(a0, qf[nt][0], sacc[mt][nt], 0, 0, 0);
            sacc[mt][nt] = __builtin_amdgcn_mfma_f32_16x16x32_bf16(a1, qf[nt][1], sacc[mt][nt], 0, 0, 0);
        }
    }
    __builtin_amdgcn_s_setprio(0);

    // ---- P = exp2(S); pack bf16 pairs X[mt][jw]; permlane-redistribute to
    // B-frag words Y[h2][p] (lane-trace-verified mapping, rounds 6-7).
    bf16x8 bp[2][2];
    #pragma unroll
    for (int nt = 0; nt < 2; ++nt) {
        unsigned int X[4][2];
        #pragma unroll
        for (int mt = 0; mt < 4; ++mt) {
            const f32x4 s = sacc[mt][nt];
            const float p0 = exp2_raw(s[0]);
            const float p1 = exp2_raw(s[1]);
            const float p2 = exp2_raw(s[2]);
            const float p3 = exp2_raw(s[3]);
            X[mt][0] = pack_trunc(p0, p1);
            X[mt][1] = pack_trunc(p2, p3);
        }
        #pragma unroll
        for (int h2 = 0; h2 < 2; ++h2) {
            unsigned int Y0, Y1, Y2, Y3;
            {
                unsigned int a = X[2 * h2][0], bb = X[2 * h2 + 1][0];
                pl32_swap(a, bb);
                pl16_swap(a, bb);
                Y0 = a; Y2 = bb;
            }
            {
                unsigned int a = X[2 * h2][1], bb = X[2 * h2 + 1][1];
                pl32_swap(a, bb);
                pl16_swap(a, bb);
                Y1 = a; Y3 = bb;
            }
            union { unsigned int u[4]; bf16x8 v; } cv;
            cv.u[0] = Y0; cv.u[1] = Y1; cv.u[2] = Y2; cv.u[3] = Y3;
            bp[nt][h2] = cv.v;
        }
    }

    // ---- O^T += V P^T; l += 1^T P (both pure register B operand) ----
    __builtin_amdgcn_s_setprio(1);
    #pragma unroll
    for (int nt = 0; nt < 2; ++nt) {
        lacc[nt] = __builtin_amdgcn_mfma_f32_16x16x32_bf16(ones, bp[nt][0], lacc[nt], 0, 0, 0);
        lacc[nt] = __builtin_amdgcn_mfma_f32_16x16x32_bf16(ones, bp[nt][1], lacc[nt], 0, 0, 0);
    }
    #pragma unroll
    for (int md = 0; md < 4; ++md) {
        const unsigned short* vr = Vc + (16 * md + lo) * 64;
        const bf16x8 v0 = *(const bf16x8*)(vr + ((q4    ) ^ xr) * 8);
        const bf16x8 v1 = *(const bf16x8*)(vr + ((q4 + 4) ^ xr) * 8);
        #pragma unroll
        for (int nt = 0; nt < 2; ++nt) {
            oacc[md][nt] = __builtin_amdgcn_mfma_f32_16x16x32_bf16(v0, bp[nt][0], oacc[md][nt], 0, 0, 0);
            oacc[md][nt] = __builtin_amdgcn_mfma_f32_16x16x32_bf16(v1, bp[nt][1], oacc[md][nt], 0, 0, 0);
        }
    }
    __builtin_amdgcn_s_setprio(0);
}

// ---------------------------------------------------------------------------
// Kernel 4: MFMA flash attention — round-4/8 configuration (HW-verified
// 50.1 us): 128 queries/block, 4 waves x 32t, triple-buffered K/V 48 KB,
// counted-vmcnt raw barriers, period-3 peeled loop, (256,3) -> VGPR 84.
// DO NOT revisit: (256,4), 40KB/period-6, and 512-thread variants all drive
// the allocator to a 64-VGPR bucket + scratch spill (rounds 5, 7, 9, 10).
// Round-12: l-sum moved to MFMA pipe (lacc), epilogue shfl reduce removed.
// ---------------------------------------------------------------------------
__global__ __launch_bounds__(256, 3)
void attn_mfma_kernel(const unsigned short* __restrict__ Qt,
                      const unsigned short* __restrict__ Kt,
                      const unsigned short* __restrict__ Vb,
                      unsigned short* __restrict__ attnT) {
    const int bh = blockIdx.x;
    const int b = bh >> 3, h = bh & 7;
    const int tBase = blockIdx.y * 128;
    const int tid = threadIdx.x;
    const int w = tid >> 6, lane = tid & 63;
    const int lo = lane & 15, q4 = lane >> 4;
    const int xr = lo & 7;

    __shared__ __align__(16) unsigned short Ks[3][64 * 64];    // [s][d] swizzled, 3x8 KB
    __shared__ __align__(16) unsigned short Vs[3][64 * 64];    // [d][s] swizzled, 3x8 KB

    const unsigned short* Kp = Kt + ((size_t)bh << 16);
    const unsigned short* Vp = Vb + ((size_t)b * 512 + h * 64) * 1024;

    // persistent Q B-frags: wave w owns t in [tBase+32w, +32), nt in {0,1}
    bf16x8 qf[2][2];
    {
        const unsigned short* Qp = Qt + ((size_t)bh * 1024 + tBase + 32 * w) * 64;
        #pragma unroll
        for (int nt = 0; nt < 2; ++nt) {
            qf[nt][0] = *(const bf16x8*)(Qp + (size_t)(16 * nt + lo) * 64 + 8 * q4);
            qf[nt][1] = *(const bf16x8*)(Qp + (size_t)(16 * nt + lo) * 64 + 32 + 8 * q4);
        }
    }

    // all-ones bf16 A-fragment for the l-sum contraction (1.0 = 0x3F80)
    bf16x8 ones;
    #pragma unroll
    for (int i = 0; i < 8; ++i) ones[i] = (short)0x3F80;

    const int rl = lane >> 3, p8 = lane & 7;

    f32x4 oacc[4][2] = {};
    f32x4 lacc[2] = {};

    // prologue: chunks 0 and 1 in flight (8 outstanding VMEM/wave)
    attn_stage(Kp, Vp, 0 * 64, Ks[0], Vs[0], w, rl, p8);
    attn_stage(Kp, Vp, 1 * 64, Ks[1], Vs[1], w, rl, p8);

    // iter 0: wait chunk 0 (allow chunk 1's 4 loads in flight), stage chunk 2
    ABAR("4");
    attn_stage(Kp, Vp, 2 * 64, Ks[2], Vs[2], w, rl, p8);
    attn_chunk(Ks[0], Vs[0], qf, ones, oacc, lacc, lo, q4, xr);

    // iters 1..12 (3-periodic, compile-time buffers)
    #pragma unroll 1
    for (int ii = 0; ii < 4; ++ii) {
        const int i = 3 * ii + 1;
        ABAR("4");
        attn_stage(Kp, Vp, (i + 2) * 64, Ks[0], Vs[0], w, rl, p8);
        attn_chunk(Ks[1], Vs[1], qf, ones, oacc, lacc, lo, q4, xr);
        ABAR("4");
        attn_stage(Kp, Vp, (i + 3) * 64, Ks[1], Vs[1], w, rl, p8);
        attn_chunk(Ks[2], Vs[2], qf, ones, oacc, lacc, lo, q4, xr);
        ABAR("4");
        attn_stage(Kp, Vp, (i + 4) * 64, Ks[2], Vs[2], w, rl, p8);
        attn_chunk(Ks[0], Vs[0], qf, ones, oacc, lacc, lo, q4, xr);
    }

    // iter 13: stage final chunk 15 -> buf 0
    ABAR("4");
    attn_stage(Kp, Vp, 15 * 64, Ks[0], Vs[0], w, rl, p8);
    attn_chunk(Ks[1], Vs[1], qf, ones, oacc, lacc, lo, q4, xr);
    // iter 14: no stage; wait chunk 14 (allow chunk 15's loads in flight)
    ABAR("4");
    attn_chunk(Ks[2], Vs[2], qf, ones, oacc, lacc, lo, q4, xr);
    // iter 15: full drain for the final chunk
    ABAR("0");
    attn_chunk(Ks[0], Vs[0], qf, ones, oacc, lacc, lo, q4, xr);

    // ---- epilogue: l[t] is complete in lacc[nt][0] (no cross-lane reduce
    // needed — the ones-MFMA contracts the full s range of each chunk).
    #pragma unroll
    for (int nt = 0; nt < 2; ++nt) {
        const float inv = 1.0f / lacc[nt][0];
        const int t = tBase + 32 * w + 16 * nt + lo;
        unsigned short* op = attnT + ((size_t)(b * 1024 + t)) * 512 + h * 64;
        #pragma unroll
        for (int md = 0; md < 4; ++md) {
            uint2 pk;
            pk.x = pack_trunc(oacc[md][nt][0] * inv, oacc[md][nt][1] * inv);
            pk.y = pack_trunc(oacc[md][nt][2] * inv, oacc[md][nt][3] * inv);
            *(uint2*)(op + 16 * md + 4 * q4) = pk;
        }
    }
}

// ---------------------------------------------------------------------------
// Kernel 5: proj GEMM + bias + residual. 1D grid + bijective XCD remap.
// ---------------------------------------------------------------------------
__global__ __launch_bounds__(256)
void proj_mfma_kernel(const unsigned short* __restrict__ wpb,
                      const unsigned short* __restrict__ attnT,
                      const float* __restrict__ proj_b,
                      const float* __restrict__ x,
                      float* __restrict__ out) {
    __shared__ __align__(16) unsigned short SMEM[3 * 8192];  // 48 KB pipeline
    const int hw_id = blockIdx.x;
    const int wk = (hw_id % 64) * 8 + hw_id / 64;     // bijective, 512 = 8*64
    const int bx = wk & 7;            // nBase index
    const int by = (wk >> 3) & 3;     // mBase index
    const int batch = wk >> 5;
    const int mBase = by * 128, nBase = bx * 128;

    f32x4 acc[4][4] = {};
    mfma_gemm_pipe((const char*)(wpb + (size_t)mBase * 512),
                   (const char*)(attnT + ((size_t)batch * 1024 + nBase) * 512),
                   SMEM, acc);

    const int tid = threadIdx.x;
    const int w = tid >> 6, lane = tid & 63;
    const int lo = lane & 15, q4 = lane >> 4;
    const int wm = w >> 1, wn = w & 1;
    const float* xb = x + (size_t)batch * 524288;
    float* ob = out + (size_t)batch * 524288;

    #pragma unroll
    for (int mi = 0; mi < 4; ++mi) {
        const int m0 = mBase + wm * 64 + mi * 16 + q4 * 4;
        const float4 bq = *(const float4*)(proj_b + m0);
        #pragma unroll
        for (int ni = 0; ni < 4; ++ni) {
            const int t = nBase + wn * 64 + ni * 16 + lo;
            const size_t o0 = (size_t)m0 * 1024 + t;
            ob[o0]          = acc[mi][ni][0] + bq.x + xb[o0];
            ob[o0 + 1024]   = acc[mi][ni][1] + bq.y + xb[o0 + 1024];
            ob[o0 + 2048]   = acc[mi][ni][2] + bq.z + xb[o0 + 2048];
            ob[o0 + 3072]   = acc[mi][ni][3] + bq.w + xb[o0 + 3072];
        }
    }
}

// ---------------------------------------------------------------------------
// Launch
// ---------------------------------------------------------------------------
extern "C" void kernel_launch(void* const* d_in, const int* in_sizes, int n_in,
                              void* d_out, int out_size, void* d_ws, size_t ws_size,
                              hipStream_t stream) {
    const float* x        = (const float*)d_in[0];
    const float* gn_gamma = (const float*)d_in[1];
    const float* gn_beta  = (const float*)d_in[2];
    const float* qkv_w    = (const float*)d_in[3];
    const float* qkv_b    = (const float*)d_in[4];
    const float* proj_w   = (const float*)d_in[5];
    const float* proj_b   = (const float*)d_in[6];
    float* out = (float*)d_out;

    // workspace layout (~86 MiB)
    char* wsc = (char*)d_ws;
    unsigned short* xnT   = (unsigned short*)(wsc);              // 16 MiB [b][t][c]
    unsigned short* Qt    = (unsigned short*)(wsc + 16777216);   // 16 MiB [bh][t][d]
    unsigned short* Kt    = (unsigned short*)(wsc + 33554432);   // 16 MiB [bh][t][d]
    unsigned short* Vb    = (unsigned short*)(wsc + 50331648);   // 16 MiB [b][d'][t]
    unsigned short* attnT = (unsigned short*)(wsc + 67108864);   // 16 MiB [b][t][c]
    unsigned short* wqb   = (unsigned short*)(wsc + 83886080);   // 1.5 MiB (wpb follows)
    unsigned short* wpb   = wqb + 786432;                        // 0.5 MiB

    // 1. GroupNorm + weight conversion (fused, independent block ranges)
    fused_pre_kernel<<<1536, 256, 0, stream>>>(x, gn_gamma, gn_beta, xnT,
                                               qkv_w, proj_w, wqb);

    // 2. QKV MFMA GEMM (writes Qt, Kt, Vb directly), XCD-swizzled 1D grid
    qkv_mfma_kernel<<<1536, 256, 0, stream>>>(wqb, xnT, qkv_b, Qt, Kt, Vb);

    // 3. MFMA flash attention -> attnT bf16 (128 queries/block, 1024 blocks)
    {
        dim3 grid(B * NUM_HEADS, HW / 128);
        attn_mfma_kernel<<<grid, 256, 0, stream>>>(Qt, Kt, Vb, attnT);
    }

    // 4. Proj MFMA GEMM + bias + residual -> fp32 out, XCD-swizzled 1D grid
    proj_mfma_kernel<<<512, 256, 0, stream>>>(wpb, attnT, proj_b, x, out);
}

// Round 13
// 200.750 us; speedup vs baseline: 1.0231x; 1.0231x over previous
//
#include <hip/hip_runtime.h>
#include <math.h>

#define NUM_HEADS 8
#define NUM_GROUPS 32
#define EPS 1e-5f

constexpr int B  = 16;
constexpr int C  = 512;
constexpr int HW = 1024;   // 32*32
constexpr int HD = 64;

typedef short bf16x8 __attribute__((ext_vector_type(8)));
typedef float f32x4  __attribute__((ext_vector_type(4)));

#define QSCALE 0.1803368801111f  /* 0.125 * log2(e): softmax done in exp2 space */

__device__ inline unsigned short f2bf(float f) {
    union { float f; unsigned int u; } v; v.f = f;
    unsigned int r = (v.u + 0x7FFFu + ((v.u >> 16) & 1u)) >> 16;
    return (unsigned short)r;
}

// pack two fp32 -> bf16 pair by truncation, single v_perm_b32
__device__ __forceinline__ unsigned int pack_trunc(float lo, float hi) {
    return __builtin_amdgcn_perm(__float_as_uint(hi), __float_as_uint(lo), 0x07060302u);
}

// raw hardware exp2: inputs bounded, OCML subnormal wrapper is dead weight.
__device__ __forceinline__ float exp2_raw(float x) {
#if __has_builtin(__builtin_amdgcn_exp2f)
    return __builtin_amdgcn_exp2f(x);
#else
    float r; asm("v_exp_f32 %0, %1" : "=v"(r) : "v"(x)); return r;
#endif
}

// async global->LDS, 16B per lane. LDS dest = wave-uniform base + lane*16.
__device__ __forceinline__ void gld_lds16(void* lds, const void* g) {
    __builtin_amdgcn_global_load_lds(
        (const __attribute__((address_space(1))) void*)g,
        (__attribute__((address_space(3))) void*)lds, 16, 0, 0);
}

// gfx950 permlane swaps. pl32: dst lanes 32..63 <-> src lanes 0..31.
// pl16: dst lanes 16..31 <-> src lanes 0..15, dst 48..63 <-> src 32..47.
__device__ __forceinline__ void pl32_swap(unsigned int& a, unsigned int& b) {
#if __has_builtin(__builtin_amdgcn_permlane32_swap)
    auto r = __builtin_amdgcn_permlane32_swap(a, b, false, false);
    a = r[0]; b = r[1];
#else
    asm volatile("v_permlane32_swap_b32 %0, %1" : "+v"(a), "+v"(b));
#endif
}
__device__ __forceinline__ void pl16_swap(unsigned int& a, unsigned int& b) {
#if __has_builtin(__builtin_amdgcn_permlane16_swap)
    auto r = __builtin_amdgcn_permlane16_swap(a, b, false, false);
    a = r[0]; b = r[1];
#else
    asm volatile("v_permlane16_swap_b32 %0, %1" : "+v"(a), "+v"(b));
#endif
}

// Counted-vmcnt barrier (T3/T4): wait for all but VM outstanding VMEM ops,
// then raw s_barrier. NEVER drains to 0 in the main loop.
#define ABAR(VM) do {                                                   \
    asm volatile("s_waitcnt vmcnt(" VM ")\n\ts_barrier" ::: "memory");  \
    __builtin_amdgcn_sched_barrier(0);                                  \
} while (0)

// ---------------------------------------------------------------------------
// Kernel 1 (fused): blocks [0,512): GroupNorm -> xnT bf16 [b][t][c];
// blocks [512,1536): weight conversion fp32 -> bf16.
// Round-13: GN reads vectorized to float4 (16 B/lane, G13) — thread owns hw
// positions 4*tid..4*tid+3 for all 16 channels (same 64 floats/thread state).
// ---------------------------------------------------------------------------
__global__ __launch_bounds__(256)
void fused_pre_kernel(const float* __restrict__ x,
                      const float* __restrict__ gamma,
                      const float* __restrict__ beta,
                      unsigned short* __restrict__ xnT,
                      const float* __restrict__ qkv_w,
                      const float* __restrict__ proj_w,
                      unsigned short* __restrict__ wqb) {
    if (blockIdx.x >= 512) {
        // ---- weight conversion ----
        const int i = (blockIdx.x - 512) * 256 + threadIdx.x;   // float4 index
        const int n1 = 786432 / 4;
        const int nt = 1048576 / 4;
        if (i >= nt) return;
        const float4 v = (i < n1) ? ((const float4*)qkv_w)[i]
                                  : ((const float4*)proj_w)[i - n1];
        ushort4 r;
        r.x = f2bf(v.x); r.y = f2bf(v.y); r.z = f2bf(v.z); r.w = f2bf(v.w);
        ((ushort4*)wqb)[i] = r;
        return;
    }
    // ---- GroupNorm ----
    const int bg = blockIdx.x;
    const int b = bg >> 5, g = bg & 31;
    const size_t base = ((size_t)b * C + (size_t)g * 16) * HW;
    const int hw0 = threadIdx.x * 4;

    float4 v4[16];
    float sum = 0.f, sumsq = 0.f;
    #pragma unroll
    for (int cl = 0; cl < 16; ++cl) {
        const float4 f = *(const float4*)(x + base + (size_t)cl * HW + hw0);
        v4[cl] = f;
        sum   += (f.x + f.y) + (f.z + f.w);
        sumsq += (f.x * f.x + f.y * f.y) + (f.z * f.z + f.w * f.w);
    }
    #pragma unroll
    for (int off = 32; off > 0; off >>= 1) {
        sum   += __shfl_down(sum, off, 64);
        sumsq += __shfl_down(sumsq, off, 64);
    }
    __shared__ float s_sum[4], s_sq[4];
    const int wid = threadIdx.x >> 6, lane = threadIdx.x & 63;
    if (lane == 0) { s_sum[wid] = sum; s_sq[wid] = sumsq; }
    __syncthreads();
    const float tsum = s_sum[0] + s_sum[1] + s_sum[2] + s_sum[3];
    const float tsq  = s_sq[0] + s_sq[1] + s_sq[2] + s_sq[3];
    const float mean = tsum * (1.0f / 16384.f);
    const float var  = tsq * (1.0f / 16384.f) - mean * mean;
    const float rstd = rsqrtf(var + EPS);

    float ga[16], be[16];
    #pragma unroll
    for (int cl = 0; cl < 16; ++cl) {
        ga[cl] = gamma[g * 16 + cl] * rstd;
        be[cl] = beta[g * 16 + cl] - mean * ga[cl];
    }

    #pragma unroll
    for (int j = 0; j < 4; ++j) {
        const int t = hw0 + j;
        unsigned short pk[16];
        #pragma unroll
        for (int cl = 0; cl < 16; ++cl) {
            const float f = (j == 0) ? v4[cl].x : (j == 1) ? v4[cl].y
                          : (j == 2) ? v4[cl].z : v4[cl].w;
            pk[cl] = f2bf(f * ga[cl] + be[cl]);
        }
        unsigned short* dst = xnT + ((size_t)(b * 1024 + t)) * 512 + g * 16;
        *(uint4*)dst = *(const uint4*)pk;
        *(uint4*)(dst + 8) = *(const uint4*)(pk + 8);
    }
}

// ---------------------------------------------------------------------------
// MFMA GEMM core: T3/T4 pipeline (HW-verified round-6). Triple-buffered LDS
// (48 KB), counted-vmcnt raw barriers, drain to 0 only before the final step.
// ---------------------------------------------------------------------------
__device__ __forceinline__ void gemm_stage(const char* __restrict__ Ab,
                                           const char* __restrict__ Bb,
                                           int step, unsigned short* As,
                                           unsigned short* Bs,
                                           int w, int lrow, int lkc) {
    #pragma unroll
    for (int i = 0; i < 2; ++i) {
        const int row = w * 32 + i * 16 + lrow;
        const int kc = lkc ^ ((row >> 1) & 3);   // swizzle k-chunk
        const size_t goff = (size_t)row * 1024 + (size_t)step * 64 + kc * 16;
        gld_lds16((char*)As + w * 2048 + i * 1024, Ab + goff);
        gld_lds16((char*)Bs + w * 2048 + i * 1024, Bb + goff);
    }
}

__device__ __forceinline__ void gemm_step(const unsigned short* __restrict__ As,
                                          const unsigned short* __restrict__ Bs,
                                          f32x4 acc[4][4],
                                          int lo, int q4, int wm, int wn) {
    bf16x8 af[4], bfr[4];
    #pragma unroll
    for (int i = 0; i < 4; ++i) {
        const int ra = wm * 64 + i * 16 + lo;
        af[i]  = *(const bf16x8*)(As + ra * 32 + (q4 ^ ((ra >> 1) & 3)) * 8);
        const int rb = wn * 64 + i * 16 + lo;
        bfr[i] = *(const bf16x8*)(Bs + rb * 32 + (q4 ^ ((rb >> 1) & 3)) * 8);
    }
    __builtin_amdgcn_s_setprio(1);
    #pragma unroll
    for (int mi = 0; mi < 4; ++mi)
        #pragma unroll
        for (int ni = 0; ni < 4; ++ni)
            acc[mi][ni] = __builtin_amdgcn_mfma_f32_16x16x32_bf16(
                af[mi], bfr[ni], acc[mi][ni], 0, 0, 0);
    __builtin_amdgcn_s_setprio(0);
}

__device__ __forceinline__ void mfma_gemm_pipe(const char* __restrict__ Ab,
                                               const char* __restrict__ Bb,
                                               unsigned short* S,   // 3*8192 shorts
                                               f32x4 acc[4][4]) {
    const int tid = threadIdx.x;
    const int w = tid >> 6, lane = tid & 63;
    const int lo = lane & 15, q4 = lane >> 4;
    const int wm = w >> 1, wn = w & 1;
    const int lrow = lane >> 2, lkc = lane & 3;

    unsigned short* A0 = S;             unsigned short* B0 = S + 4096;
    unsigned short* A1 = S + 8192;      unsigned short* B1 = S + 12288;
    unsigned short* A2 = S + 16384;     unsigned short* B2 = S + 20480;

    gemm_stage(Ab, Bb, 0, A0, B0, w, lrow, lkc);
    gemm_stage(Ab, Bb, 1, A1, B1, w, lrow, lkc);
    ABAR("4");                                      // step 0 landed
    gemm_stage(Ab, Bb, 2, A2, B2, w, lrow, lkc);
    gemm_step(A0, B0, acc, lo, q4, wm, wn);

    #pragma unroll 1
    for (int ii = 0; ii < 4; ++ii) {
        const int i = 3 * ii + 1;
        ABAR("4");
        gemm_stage(Ab, Bb, i + 2, A0, B0, w, lrow, lkc);
        gemm_step(A1, B1, acc, lo, q4, wm, wn);
        ABAR("4");
        gemm_stage(Ab, Bb, i + 3, A1, B1, w, lrow, lkc);
        gemm_step(A2, B2, acc, lo, q4, wm, wn);
        ABAR("4");
        gemm_stage(Ab, Bb, i + 4, A2, B2, w, lrow, lkc);
        gemm_step(A0, B0, acc, lo, q4, wm, wn);
    }

    ABAR("4");
    gemm_stage(Ab, Bb, 15, A0, B0, w, lrow, lkc);
    gemm_step(A1, B1, acc, lo, q4, wm, wn);
    ABAR("4");
    gemm_step(A2, B2, acc, lo, q4, wm, wn);
    ABAR("0");
    gemm_step(A0, B0, acc, lo, q4, wm, wn);
}

// ---------------------------------------------------------------------------
// Kernel 3: QKV projection GEMM. 1D grid + bijective XCD remap (T1).
// ---------------------------------------------------------------------------
__global__ __launch_bounds__(256)
void qkv_mfma_kernel(const unsigned short* __restrict__ wqb,
                     const unsigned short* __restrict__ xnT,
                     const float* __restrict__ qkv_b,
                     unsigned short* __restrict__ Qt,
                     unsigned short* __restrict__ Kt,
                     unsigned short* __restrict__ Vb) {
    __shared__ __align__(16) unsigned short SMEM[3 * 8192];  // 48 KB pipeline; reused by V epilogue
    const int hw_id = blockIdx.x;
    const int wk = (hw_id % 192) * 8 + hw_id / 192;   // bijective, 1536 = 8*192
    const int bx = wk & 7;            // nBase index
    const int by = (wk >> 3) % 12;    // mBase index
    const int batch = wk / 96;
    const int mBase = by * 128, nBase = bx * 128;

    f32x4 acc[4][4] = {};
    mfma_gemm_pipe((const char*)(wqb + (size_t)mBase * 512),
                   (const char*)(xnT + ((size_t)batch * 1024 + nBase) * 512),
                   SMEM, acc);

    const int tid = threadIdx.x;
    const int w = tid >> 6, lane = tid & 63;
    const int lo = lane & 15, q4 = lane >> 4;
    const int wm = w >> 1, wn = w & 1;
    const int mw = mBase + wm * 64;          // head-aligned 64-row chunk
    const int tb = nBase + wn * 64;

    __syncthreads();   // all waves done with GEMM LDS

    if (mw < 1024) {
        const bool isQ = mw < 512;
        const int head = (mw >> 6) & 7;
        unsigned short* dst = (isQ ? Qt : Kt) + (((size_t)batch * 8 + head) << 16);
        const float sc = isQ ? QSCALE : 1.0f;
        #pragma unroll
        for (int mi = 0; mi < 4; ++mi) {
            const float4 bq = *(const float4*)(qkv_b + mw + mi * 16 + q4 * 4);
            #pragma unroll
            for (int ni = 0; ni < 4; ++ni) {
                const int t = tb + ni * 16 + lo;
                ushort4 pk;
                pk.x = f2bf((acc[mi][ni][0] + bq.x) * sc);
                pk.y = f2bf((acc[mi][ni][1] + bq.y) * sc);
                pk.z = f2bf((acc[mi][ni][2] + bq.z) * sc);
                pk.w = f2bf((acc[mi][ni][3] + bq.w) * sc);
                *(ushort4*)(dst + (size_t)t * 64 + mi * 16 + q4 * 4) = pk;
            }
        }
    } else {
        // V: LDS transpose -> coalesced uint4 stores into Vb[b][d][t].
        unsigned short* T = SMEM + w * 2048;         // 32 x 64 shorts
        unsigned short* Vrow = Vb + (size_t)batch * 524288 + (size_t)(mw - 1024) * 1024 + tb;
        const int rl8 = lane >> 3, c8 = lane & 7;
        #pragma unroll
        for (int p = 0; p < 2; ++p) {
            #pragma unroll
            for (int mi2 = 0; mi2 < 2; ++mi2) {
                const int mi = 2 * p + mi2;
                const float4 bq = *(const float4*)(qkv_b + mw + mi * 16 + q4 * 4);
                const int dl = mi2 * 16 + q4 * 4;
                #pragma unroll
                for (int ni = 0; ni < 4; ++ni) {
                    const int tl = ni * 16 + lo;
                    T[(dl + 0) * 64 + tl] = f2bf(acc[mi][ni][0] + bq.x);
                    T[(dl + 1) * 64 + tl] = f2bf(acc[mi][ni][1] + bq.y);
                    T[(dl + 2) * 64 + tl] = f2bf(acc[mi][ni][2] + bq.z);
                    T[(dl + 3) * 64 + tl] = f2bf(acc[mi][ni][3] + bq.w);
                }
            }
            #pragma unroll
            for (int i = 0; i < 4; ++i) {
                const int dl = i * 8 + rl8;
                const uint4 val = *(const uint4*)&T[dl * 64 + c8 * 8];
                *(uint4*)(Vrow + (size_t)(p * 32 + dl) * 1024 + c8 * 8) = val;
            }
        }
    }
}

// ---------------------------------------------------------------------------
// Attn helpers (round-4 verified): stage one 64-s K/V chunk; compute one chunk.
// l-sum via MFMA ones-contraction (round-12 verified: lacc accumulates
// l[t] = sum_s P on the MFMA pipe, D col = lo = t, rows identical).
// ---------------------------------------------------------------------------
__device__ __forceinline__ void attn_stage(const unsigned short* __restrict__ Kp,
                                           const unsigned short* __restrict__ Vp,
                                           int s0, unsigned short* Kd,
                                           unsigned short* Vd,
                                           int w, int rl, int p8) {
    #pragma unroll
    for (int cc = 0; cc < 2; ++cc) {
        const int r = 16 * w + 8 * cc + rl;
        const int jj = p8 ^ (r & 7);
        gld_lds16(Kd + (16 * w + 8 * cc) * 64, Kp + (size_t)(s0 + r) * 64 + jj * 8);
        gld_lds16(Vd + (16 * w + 8 * cc) * 64, Vp + (size_t)r * 1024 + s0 + jj * 8);
    }
}

__device__ __forceinline__ void attn_chunk(const unsigned short* __restrict__ Kc,
                                           const unsigned short* __restrict__ Vc,
                                           const bf16x8 (&qf)[2][2],
                                           const bf16x8 ones,
                                           f32x4 (&oacc)[4][2], f32x4 (&lacc)[2],
                                           int lo, int q4, int xr) {
    // ---- S^T = K^T Q : sacc[mt][nt], D row s_local = 4*q4+reg, col t = lo
    f32x4 sacc[4][2] = {};
    __builtin_amdgcn_s_setprio(1);
    #pragma unroll
    for (int mt = 0; mt < 4; ++mt) {
        const unsigned short* kr = Kc + (16 * mt + lo) * 64;
        const bf16x8 a0 = *(const bf16x8*)(kr + ((q4    ) ^ xr) * 8);
        const bf16x8 a1 = *(const bf16x8*)(kr + ((q4 + 4) ^ xr) * 8);
        #pragma unroll
        for (int nt = 0; nt < 2; ++nt) {
            sacc[mt][nt] = __builtin_amdgcn_mfma_f32_16x16x32_bf16(a0, qf[nt][0], sacc[mt][nt], 0, 0, 0);
            sacc[mt][nt] = __builtin_amdgcn_mfma_f32_16x16x32_bf16(a1, qf[nt][1], sacc[mt][nt], 0, 0, 0);
        }
    }
    __builtin_amdgcn_s_setprio(0);

    // ---- P = exp2(S); pack bf16 pairs X[mt][jw]; permlane-redistribute to
    // B-frag words Y[h2][p] (lane-trace-verified mapping, rounds 6-7).
    bf16x8 bp[2][2];
    #pragma unroll
    for (int nt = 0; nt < 2; ++nt) {
        unsigned int X[4][2];
        #pragma unroll
        for (int mt = 0; mt < 4; ++mt) {
            const f32x4 s = sacc[mt][nt];
            const float p0 = exp2_raw(s[0]);
            const float p1 = exp2_raw(s[1]);
            const float p2 = exp2_raw(s[2]);
            const float p3 = exp2_raw(s[3]);
            X[mt][0] = pack_trunc(p0, p1);
            X[mt][1] = pack_trunc(p2, p3);
        }
        #pragma unroll
        for (int h2 = 0; h2 < 2; ++h2) {
            unsigned int Y0, Y1, Y2, Y3;
            {
                unsigned int a = X[2 * h2][0], bb = X[2 * h2 + 1][0];
                pl32_swap(a, bb);
                pl16_swap(a, bb);
                Y0 = a; Y2 = bb;
            }
            {
                unsigned int a = X[2 * h2][1], bb = X[2 * h2 + 1][1];
                pl32_swap(a, bb);
                pl16_swap(a, bb);
                Y1 = a; Y3 = bb;
            }
            union { unsigned int u[4]; bf16x8 v; } cv;
            cv.u[0] = Y0; cv.u[1] = Y1; cv.u[2] = Y2; cv.u[3] = Y3;
            bp[nt][h2] = cv.v;
        }
    }

    // ---- O^T += V P^T; l += 1^T P (both pure register B operand) ----
    __builtin_amdgcn_s_setprio(1);
    #pragma unroll
    for (int nt = 0; nt < 2; ++nt) {
        lacc[nt] = __builtin_amdgcn_mfma_f32_16x16x32_bf16(ones, bp[nt][0], lacc[nt], 0, 0, 0);
        lacc[nt] = __builtin_amdgcn_mfma_f32_16x16x32_bf16(ones, bp[nt][1], lacc[nt], 0, 0, 0);
    }
    #pragma unroll
    for (int md = 0; md < 4; ++md) {
        const unsigned short* vr = Vc + (16 * md + lo) * 64;
        const bf16x8 v0 = *(const bf16x8*)(vr + ((q4    ) ^ xr) * 8);
        const bf16x8 v1 = *(const bf16x8*)(vr + ((q4 + 4) ^ xr) * 8);
        #pragma unroll
        for (int nt = 0; nt < 2; ++nt) {
            oacc[md][nt] = __builtin_amdgcn_mfma_f32_16x16x32_bf16(v0, bp[nt][0], oacc[md][nt], 0, 0, 0);
            oacc[md][nt] = __builtin_amdgcn_mfma_f32_16x16x32_bf16(v1, bp[nt][1], oacc[md][nt], 0, 0, 0);
        }
    }
    __builtin_amdgcn_s_setprio(0);
}

// ---------------------------------------------------------------------------
// Kernel 4: MFMA flash attention — round-12 verified config (46.7 us, VGPR 72):
// 128 queries/block, 4 waves x 32t, triple-buffered K/V 48 KB, counted-vmcnt
// raw barriers, period-3 peeled loop, (256,3), MFMA l-sum.
// DO NOT revisit: (256,4), 40KB/period-6, and 512-thread variants all drive
// the allocator to a 64-VGPR bucket + scratch spill (rounds 5, 7, 9, 10).
// ---------------------------------------------------------------------------
__global__ __launch_bounds__(256, 3)
void attn_mfma_kernel(const unsigned short* __restrict__ Qt,
                      const unsigned short* __restrict__ Kt,
                      const unsigned short* __restrict__ Vb,
                      unsigned short* __restrict__ attnT) {
    const int bh = blockIdx.x;
    const int b = bh >> 3, h = bh & 7;
    const int tBase = blockIdx.y * 128;
    const int tid = threadIdx.x;
    const int w = tid >> 6, lane = tid & 63;
    const int lo = lane & 15, q4 = lane >> 4;
    const int xr = lo & 7;

    __shared__ __align__(16) unsigned short Ks[3][64 * 64];    // [s][d] swizzled, 3x8 KB
    __shared__ __align__(16) unsigned short Vs[3][64 * 64];    // [d][s] swizzled, 3x8 KB

    const unsigned short* Kp = Kt + ((size_t)bh << 16);
    const unsigned short* Vp = Vb + ((size_t)b * 512 + h * 64) * 1024;

    // persistent Q B-frags: wave w owns t in [tBase+32w, +32), nt in {0,1}
    bf16x8 qf[2][2];
    {
        const unsigned short* Qp = Qt + ((size_t)bh * 1024 + tBase + 32 * w) * 64;
        #pragma unroll
        for (int nt = 0; nt < 2; ++nt) {
            qf[nt][0] = *(const bf16x8*)(Qp + (size_t)(16 * nt + lo) * 64 + 8 * q4);
            qf[nt][1] = *(const bf16x8*)(Qp + (size_t)(16 * nt + lo) * 64 + 32 + 8 * q4);
        }
    }

    // all-ones bf16 A-fragment for the l-sum contraction (1.0 = 0x3F80)
    bf16x8 ones;
    #pragma unroll
    for (int i = 0; i < 8; ++i) ones[i] = (short)0x3F80;

    const int rl = lane >> 3, p8 = lane & 7;

    f32x4 oacc[4][2] = {};
    f32x4 lacc[2] = {};

    // prologue: chunks 0 and 1 in flight (8 outstanding VMEM/wave)
    attn_stage(Kp, Vp, 0 * 64, Ks[0], Vs[0], w, rl, p8);
    attn_stage(Kp, Vp, 1 * 64, Ks[1], Vs[1], w, rl, p8);

    // iter 0: wait chunk 0 (allow chunk 1's 4 loads in flight), stage chunk 2
    ABAR("4");
    attn_stage(Kp, Vp, 2 * 64, Ks[2], Vs[2], w, rl, p8);
    attn_chunk(Ks[0], Vs[0], qf, ones, oacc, lacc, lo, q4, xr);

    // iters 1..12 (3-periodic, compile-time buffers)
    #pragma unroll 1
    for (int ii = 0; ii < 4; ++ii) {
        const int i = 3 * ii + 1;
        ABAR("4");
        attn_stage(Kp, Vp, (i + 2) * 64, Ks[0], Vs[0], w, rl, p8);
        attn_chunk(Ks[1], Vs[1], qf, ones, oacc, lacc, lo, q4, xr);
        ABAR("4");
        attn_stage(Kp, Vp, (i + 3) * 64, Ks[1], Vs[1], w, rl, p8);
        attn_chunk(Ks[2], Vs[2], qf, ones, oacc, lacc, lo, q4, xr);
        ABAR("4");
        attn_stage(Kp, Vp, (i + 4) * 64, Ks[2], Vs[2], w, rl, p8);
        attn_chunk(Ks[0], Vs[0], qf, ones, oacc, lacc, lo, q4, xr);
    }

    // iter 13: stage final chunk 15 -> buf 0
    ABAR("4");
    attn_stage(Kp, Vp, 15 * 64, Ks[0], Vs[0], w, rl, p8);
    attn_chunk(Ks[1], Vs[1], qf, ones, oacc, lacc, lo, q4, xr);
    // iter 14: no stage; wait chunk 14 (allow chunk 15's loads in flight)
    ABAR("4");
    attn_chunk(Ks[2], Vs[2], qf, ones, oacc, lacc, lo, q4, xr);
    // iter 15: full drain for the final chunk
    ABAR("0");
    attn_chunk(Ks[0], Vs[0], qf, ones, oacc, lacc, lo, q4, xr);

    // ---- epilogue: l[t] complete in lacc[nt][0]; no cross-lane reduce.
    #pragma unroll
    for (int nt = 0; nt < 2; ++nt) {
        const float inv = 1.0f / lacc[nt][0];
        const int t = tBase + 32 * w + 16 * nt + lo;
        unsigned short* op = attnT + ((size_t)(b * 1024 + t)) * 512 + h * 64;
        #pragma unroll
        for (int md = 0; md < 4; ++md) {
            uint2 pk;
            pk.x = pack_trunc(oacc[md][nt][0] * inv, oacc[md][nt][1] * inv);
            pk.y = pack_trunc(oacc[md][nt][2] * inv, oacc[md][nt][3] * inv);
            *(uint2*)(op + 16 * md + 4 * q4) = pk;
        }
    }
}

// ---------------------------------------------------------------------------
// Kernel 5: proj GEMM + bias + residual. 1D grid + bijective XCD remap.
// ---------------------------------------------------------------------------
__global__ __launch_bounds__(256)
void proj_mfma_kernel(const unsigned short* __restrict__ wpb,
                      const unsigned short* __restrict__ attnT,
                      const float* __restrict__ proj_b,
                      const float* __restrict__ x,
                      float* __restrict__ out) {
    __shared__ __align__(16) unsigned short SMEM[3 * 8192];  // 48 KB pipeline
    const int hw_id = blockIdx.x;
    const int wk = (hw_id % 64) * 8 + hw_id / 64;     // bijective, 512 = 8*64
    const int bx = wk & 7;            // nBase index
    const int by = (wk >> 3) & 3;     // mBase index
    const int batch = wk >> 5;
    const int mBase = by * 128, nBase = bx * 128;

    f32x4 acc[4][4] = {};
    mfma_gemm_pipe((const char*)(wpb + (size_t)mBase * 512),
                   (const char*)(attnT + ((size_t)batch * 1024 + nBase) * 512),
                   SMEM, acc);

    const int tid = threadIdx.x;
    const int w = tid >> 6, lane = tid & 63;
    const int lo = lane & 15, q4 = lane >> 4;
    const int wm = w >> 1, wn = w & 1;
    const float* xb = x + (size_t)batch * 524288;
    float* ob = out + (size_t)batch * 524288;

    #pragma unroll
    for (int mi = 0; mi < 4; ++mi) {
        const int m0 = mBase + wm * 64 + mi * 16 + q4 * 4;
        const float4 bq = *(const float4*)(proj_b + m0);
        #pragma unroll
        for (int ni = 0; ni < 4; ++ni) {
            const int t = nBase + wn * 64 + ni * 16 + lo;
            const size_t o0 = (size_t)m0 * 1024 + t;
            ob[o0]          = acc[mi][ni][0] + bq.x + xb[o0];
            ob[o0 + 1024]   = acc[mi][ni][1] + bq.y + xb[o0 + 1024];
            ob[o0 + 2048]   = acc[mi][ni][2] + bq.z + xb[o0 + 2048];
            ob[o0 + 3072]   = acc[mi][ni][3] + bq.w + xb[o0 + 3072];
        }
    }
}

// ---------------------------------------------------------------------------
// Launch
// ---------------------------------------------------------------------------
extern "C" void kernel_launch(void* const* d_in, const int* in_sizes, int n_in,
                              void* d_out, int out_size, void* d_ws, size_t ws_size,
                              hipStream_t stream) {
    const float* x        = (const float*)d_in[0];
    const float* gn_gamma = (const float*)d_in[1];
    const float* gn_beta  = (const float*)d_in[2];
    const float* qkv_w    = (const float*)d_in[3];
    const float* qkv_b    = (const float*)d_in[4];
    const float* proj_w   = (const float*)d_in[5];
    const float* proj_b   = (const float*)d_in[6];
    float* out = (float*)d_out;

    // workspace layout (~86 MiB)
    char* wsc = (char*)d_ws;
    unsigned short* xnT   = (unsigned short*)(wsc);              // 16 MiB [b][t][c]
    unsigned short* Qt    = (unsigned short*)(wsc + 16777216);   // 16 MiB [bh][t][d]
    unsigned short* Kt    = (unsigned short*)(wsc + 33554432);   // 16 MiB [bh][t][d]
    unsigned short* Vb    = (unsigned short*)(wsc + 50331648);   // 16 MiB [b][d'][t]
    unsigned short* attnT = (unsigned short*)(wsc + 67108864);   // 16 MiB [b][t][c]
    unsigned short* wqb   = (unsigned short*)(wsc + 83886080);   // 1.5 MiB (wpb follows)
    unsigned short* wpb   = wqb + 786432;                        // 0.5 MiB

    // 1. GroupNorm + weight conversion (fused, independent block ranges)
    fused_pre_kernel<<<1536, 256, 0, stream>>>(x, gn_gamma, gn_beta, xnT,
                                               qkv_w, proj_w, wqb);

    // 2. QKV MFMA GEMM (writes Qt, Kt, Vb directly), XCD-swizzled 1D grid
    qkv_mfma_kernel<<<1536, 256, 0, stream>>>(wqb, xnT, qkv_b, Qt, Kt, Vb);

    // 3. MFMA flash attention -> attnT bf16 (128 queries/block, 1024 blocks)
    {
        dim3 grid(B * NUM_HEADS, HW / 128);
        attn_mfma_kernel<<<grid, 256, 0, stream>>>(Qt, Kt, Vb, attnT);
    }

    // 4. Proj MFMA GEMM + bias + residual -> fp32 out, XCD-swizzled 1D grid
    proj_mfma_kernel<<<512, 256, 0, stream>>>(wpb, attnT, proj_b, x, out);
}

// Round 14
// 199.254 us; speedup vs baseline: 1.0308x; 1.0075x over previous
//
#include <hip/hip_runtime.h>
#include <math.h>

#define NUM_HEADS 8
#define NUM_GROUPS 32
#define EPS 1e-5f

constexpr int B  = 16;
constexpr int C  = 512;
constexpr int HW = 1024;   // 32*32
constexpr int HD = 64;

typedef short bf16x8 __attribute__((ext_vector_type(8)));
typedef float f32x4  __attribute__((ext_vector_type(4)));

#define QSCALE 0.1803368801111f  /* 0.125 * log2(e): softmax done in exp2 space */

__device__ inline unsigned short f2bf(float f) {
    union { float f; unsigned int u; } v; v.f = f;
    unsigned int r = (v.u + 0x7FFFu + ((v.u >> 16) & 1u)) >> 16;
    return (unsigned short)r;
}

// pack two fp32 -> bf16 pair by truncation, single v_perm_b32
__device__ __forceinline__ unsigned int pack_trunc(float lo, float hi) {
    return __builtin_amdgcn_perm(__float_as_uint(hi), __float_as_uint(lo), 0x07060302u);
}

// raw hardware exp2: inputs bounded, OCML subnormal wrapper is dead weight.
__device__ __forceinline__ float exp2_raw(float x) {
#if __has_builtin(__builtin_amdgcn_exp2f)
    return __builtin_amdgcn_exp2f(x);
#else
    float r; asm("v_exp_f32 %0, %1" : "=v"(r) : "v"(x)); return r;
#endif
}

// async global->LDS, 16B per lane. LDS dest = wave-uniform base + lane*16.
__device__ __forceinline__ void gld_lds16(void* lds, const void* g) {
    __builtin_amdgcn_global_load_lds(
        (const __attribute__((address_space(1))) void*)g,
        (__attribute__((address_space(3))) void*)lds, 16, 0, 0);
}

// gfx950 permlane swaps. pl32: dst lanes 32..63 <-> src lanes 0..31.
// pl16: dst lanes 16..31 <-> src lanes 0..15, dst 48..63 <-> src 32..47.
__device__ __forceinline__ void pl32_swap(unsigned int& a, unsigned int& b) {
#if __has_builtin(__builtin_amdgcn_permlane32_swap)
    auto r = __builtin_amdgcn_permlane32_swap(a, b, false, false);
    a = r[0]; b = r[1];
#else
    asm volatile("v_permlane32_swap_b32 %0, %1" : "+v"(a), "+v"(b));
#endif
}
__device__ __forceinline__ void pl16_swap(unsigned int& a, unsigned int& b) {
#if __has_builtin(__builtin_amdgcn_permlane16_swap)
    auto r = __builtin_amdgcn_permlane16_swap(a, b, false, false);
    a = r[0]; b = r[1];
#else
    asm volatile("v_permlane16_swap_b32 %0, %1" : "+v"(a), "+v"(b));
#endif
}

// Counted-vmcnt barrier (T3/T4): wait for all but VM outstanding VMEM ops,
// then raw s_barrier. NEVER drains to 0 in the main loop.
#define ABAR(VM) do {                                                   \
    asm volatile("s_waitcnt vmcnt(" VM ")\n\ts_barrier" ::: "memory");  \
    __builtin_amdgcn_sched_barrier(0);                                  \
} while (0)

// ---------------------------------------------------------------------------
// Kernel 1 (fused): blocks [0,512): GroupNorm -> xnT bf16 [b][t][c];
// blocks [512,1536): weight conversion fp32 -> bf16.
// GN reads vectorized to float4 (16 B/lane, G13) — verified round 13.
// ---------------------------------------------------------------------------
__global__ __launch_bounds__(256)
void fused_pre_kernel(const float* __restrict__ x,
                      const float* __restrict__ gamma,
                      const float* __restrict__ beta,
                      unsigned short* __restrict__ xnT,
                      const float* __restrict__ qkv_w,
                      const float* __restrict__ proj_w,
                      unsigned short* __restrict__ wqb) {
    if (blockIdx.x >= 512) {
        // ---- weight conversion ----
        const int i = (blockIdx.x - 512) * 256 + threadIdx.x;   // float4 index
        const int n1 = 786432 / 4;
        const int nt = 1048576 / 4;
        if (i >= nt) return;
        const float4 v = (i < n1) ? ((const float4*)qkv_w)[i]
                                  : ((const float4*)proj_w)[i - n1];
        ushort4 r;
        r.x = f2bf(v.x); r.y = f2bf(v.y); r.z = f2bf(v.z); r.w = f2bf(v.w);
        ((ushort4*)wqb)[i] = r;
        return;
    }
    // ---- GroupNorm ----
    const int bg = blockIdx.x;
    const int b = bg >> 5, g = bg & 31;
    const size_t base = ((size_t)b * C + (size_t)g * 16) * HW;
    const int hw0 = threadIdx.x * 4;

    float4 v4[16];
    float sum = 0.f, sumsq = 0.f;
    #pragma unroll
    for (int cl = 0; cl < 16; ++cl) {
        const float4 f = *(const float4*)(x + base + (size_t)cl * HW + hw0);
        v4[cl] = f;
        sum   += (f.x + f.y) + (f.z + f.w);
        sumsq += (f.x * f.x + f.y * f.y) + (f.z * f.z + f.w * f.w);
    }
    #pragma unroll
    for (int off = 32; off > 0; off >>= 1) {
        sum   += __shfl_down(sum, off, 64);
        sumsq += __shfl_down(sumsq, off, 64);
    }
    __shared__ float s_sum[4], s_sq[4];
    const int wid = threadIdx.x >> 6, lane = threadIdx.x & 63;
    if (lane == 0) { s_sum[wid] = sum; s_sq[wid] = sumsq; }
    __syncthreads();
    const float tsum = s_sum[0] + s_sum[1] + s_sum[2] + s_sum[3];
    const float tsq  = s_sq[0] + s_sq[1] + s_sq[2] + s_sq[3];
    const float mean = tsum * (1.0f / 16384.f);
    const float var  = tsq * (1.0f / 16384.f) - mean * mean;
    const float rstd = rsqrtf(var + EPS);

    float ga[16], be[16];
    #pragma unroll
    for (int cl = 0; cl < 16; ++cl) {
        ga[cl] = gamma[g * 16 + cl] * rstd;
        be[cl] = beta[g * 16 + cl] - mean * ga[cl];
    }

    #pragma unroll
    for (int j = 0; j < 4; ++j) {
        const int t = hw0 + j;
        unsigned short pk[16];
        #pragma unroll
        for (int cl = 0; cl < 16; ++cl) {
            const float f = (j == 0) ? v4[cl].x : (j == 1) ? v4[cl].y
                          : (j == 2) ? v4[cl].z : v4[cl].w;
            pk[cl] = f2bf(f * ga[cl] + be[cl]);
        }
        unsigned short* dst = xnT + ((size_t)(b * 1024 + t)) * 512 + g * 16;
        *(uint4*)dst = *(const uint4*)pk;
        *(uint4*)(dst + 8) = *(const uint4*)(pk + 8);
    }
}

// ---------------------------------------------------------------------------
// MFMA GEMM core: T3/T4 pipeline (HW-verified round-6). Triple-buffered LDS
// (48 KB), counted-vmcnt raw barriers, drain to 0 only before the final step.
// ---------------------------------------------------------------------------
__device__ __forceinline__ void gemm_stage(const char* __restrict__ Ab,
                                           const char* __restrict__ Bb,
                                           int step, unsigned short* As,
                                           unsigned short* Bs,
                                           int w, int lrow, int lkc) {
    #pragma unroll
    for (int i = 0; i < 2; ++i) {
        const int row = w * 32 + i * 16 + lrow;
        const int kc = lkc ^ ((row >> 1) & 3);   // swizzle k-chunk
        const size_t goff = (size_t)row * 1024 + (size_t)step * 64 + kc * 16;
        gld_lds16((char*)As + w * 2048 + i * 1024, Ab + goff);
        gld_lds16((char*)Bs + w * 2048 + i * 1024, Bb + goff);
    }
}

__device__ __forceinline__ void gemm_step(const unsigned short* __restrict__ As,
                                          const unsigned short* __restrict__ Bs,
                                          f32x4 acc[4][4],
                                          int lo, int q4, int wm, int wn) {
    bf16x8 af[4], bfr[4];
    #pragma unroll
    for (int i = 0; i < 4; ++i) {
        const int ra = wm * 64 + i * 16 + lo;
        af[i]  = *(const bf16x8*)(As + ra * 32 + (q4 ^ ((ra >> 1) & 3)) * 8);
        const int rb = wn * 64 + i * 16 + lo;
        bfr[i] = *(const bf16x8*)(Bs + rb * 32 + (q4 ^ ((rb >> 1) & 3)) * 8);
    }
    __builtin_amdgcn_s_setprio(1);
    #pragma unroll
    for (int mi = 0; mi < 4; ++mi)
        #pragma unroll
        for (int ni = 0; ni < 4; ++ni)
            acc[mi][ni] = __builtin_amdgcn_mfma_f32_16x16x32_bf16(
                af[mi], bfr[ni], acc[mi][ni], 0, 0, 0);
    __builtin_amdgcn_s_setprio(0);
}

__device__ __forceinline__ void mfma_gemm_pipe(const char* __restrict__ Ab,
                                               const char* __restrict__ Bb,
                                               unsigned short* S,   // 3*8192 shorts
                                               f32x4 acc[4][4]) {
    const int tid = threadIdx.x;
    const int w = tid >> 6, lane = tid & 63;
    const int lo = lane & 15, q4 = lane >> 4;
    const int wm = w >> 1, wn = w & 1;
    const int lrow = lane >> 2, lkc = lane & 3;

    unsigned short* A0 = S;             unsigned short* B0 = S + 4096;
    unsigned short* A1 = S + 8192;      unsigned short* B1 = S + 12288;
    unsigned short* A2 = S + 16384;     unsigned short* B2 = S + 20480;

    gemm_stage(Ab, Bb, 0, A0, B0, w, lrow, lkc);
    gemm_stage(Ab, Bb, 1, A1, B1, w, lrow, lkc);
    ABAR("4");                                      // step 0 landed
    gemm_stage(Ab, Bb, 2, A2, B2, w, lrow, lkc);
    gemm_step(A0, B0, acc, lo, q4, wm, wn);

    #pragma unroll 1
    for (int ii = 0; ii < 4; ++ii) {
        const int i = 3 * ii + 1;
        ABAR("4");
        gemm_stage(Ab, Bb, i + 2, A0, B0, w, lrow, lkc);
        gemm_step(A1, B1, acc, lo, q4, wm, wn);
        ABAR("4");
        gemm_stage(Ab, Bb, i + 3, A1, B1, w, lrow, lkc);
        gemm_step(A2, B2, acc, lo, q4, wm, wn);
        ABAR("4");
        gemm_stage(Ab, Bb, i + 4, A2, B2, w, lrow, lkc);
        gemm_step(A0, B0, acc, lo, q4, wm, wn);
    }

    ABAR("4");
    gemm_stage(Ab, Bb, 15, A0, B0, w, lrow, lkc);
    gemm_step(A1, B1, acc, lo, q4, wm, wn);
    ABAR("4");
    gemm_step(A2, B2, acc, lo, q4, wm, wn);
    ABAR("0");
    gemm_step(A0, B0, acc, lo, q4, wm, wn);
}

// ---------------------------------------------------------------------------
// Kernel 3: QKV projection GEMM. 1D grid + bijective XCD remap (T1).
// ---------------------------------------------------------------------------
__global__ __launch_bounds__(256)
void qkv_mfma_kernel(const unsigned short* __restrict__ wqb,
                     const unsigned short* __restrict__ xnT,
                     const float* __restrict__ qkv_b,
                     unsigned short* __restrict__ Qt,
                     unsigned short* __restrict__ Kt,
                     unsigned short* __restrict__ Vb) {
    __shared__ __align__(16) unsigned short SMEM[3 * 8192];  // 48 KB pipeline; reused by V epilogue
    const int hw_id = blockIdx.x;
    const int wk = (hw_id % 192) * 8 + hw_id / 192;   // bijective, 1536 = 8*192
    const int bx = wk & 7;            // nBase index
    const int by = (wk >> 3) % 12;    // mBase index
    const int batch = wk / 96;
    const int mBase = by * 128, nBase = bx * 128;

    f32x4 acc[4][4] = {};
    mfma_gemm_pipe((const char*)(wqb + (size_t)mBase * 512),
                   (const char*)(xnT + ((size_t)batch * 1024 + nBase) * 512),
                   SMEM, acc);

    const int tid = threadIdx.x;
    const int w = tid >> 6, lane = tid & 63;
    const int lo = lane & 15, q4 = lane >> 4;
    const int wm = w >> 1, wn = w & 1;
    const int mw = mBase + wm * 64;          // head-aligned 64-row chunk
    const int tb = nBase + wn * 64;

    __syncthreads();   // all waves done with GEMM LDS

    if (mw < 1024) {
        const bool isQ = mw < 512;
        const int head = (mw >> 6) & 7;
        unsigned short* dst = (isQ ? Qt : Kt) + (((size_t)batch * 8 + head) << 16);
        const float sc = isQ ? QSCALE : 1.0f;
        #pragma unroll
        for (int mi = 0; mi < 4; ++mi) {
            const float4 bq = *(const float4*)(qkv_b + mw + mi * 16 + q4 * 4);
            #pragma unroll
            for (int ni = 0; ni < 4; ++ni) {
                const int t = tb + ni * 16 + lo;
                ushort4 pk;
                pk.x = f2bf((acc[mi][ni][0] + bq.x) * sc);
                pk.y = f2bf((acc[mi][ni][1] + bq.y) * sc);
                pk.z = f2bf((acc[mi][ni][2] + bq.z) * sc);
                pk.w = f2bf((acc[mi][ni][3] + bq.w) * sc);
                *(ushort4*)(dst + (size_t)t * 64 + mi * 16 + q4 * 4) = pk;
            }
        }
    } else {
        // V: LDS transpose -> coalesced uint4 stores into Vb[b][d][t].
        unsigned short* T = SMEM + w * 2048;         // 32 x 64 shorts
        unsigned short* Vrow = Vb + (size_t)batch * 524288 + (size_t)(mw - 1024) * 1024 + tb;
        const int rl8 = lane >> 3, c8 = lane & 7;
        #pragma unroll
        for (int p = 0; p < 2; ++p) {
            #pragma unroll
            for (int mi2 = 0; mi2 < 2; ++mi2) {
                const int mi = 2 * p + mi2;
                const float4 bq = *(const float4*)(qkv_b + mw + mi * 16 + q4 * 4);
                const int dl = mi2 * 16 + q4 * 4;
                #pragma unroll
                for (int ni = 0; ni < 4; ++ni) {
                    const int tl = ni * 16 + lo;
                    T[(dl + 0) * 64 + tl] = f2bf(acc[mi][ni][0] + bq.x);
                    T[(dl + 1) * 64 + tl] = f2bf(acc[mi][ni][1] + bq.y);
                    T[(dl + 2) * 64 + tl] = f2bf(acc[mi][ni][2] + bq.z);
                    T[(dl + 3) * 64 + tl] = f2bf(acc[mi][ni][3] + bq.w);
                }
            }
            #pragma unroll
            for (int i = 0; i < 4; ++i) {
                const int dl = i * 8 + rl8;
                const uint4 val = *(const uint4*)&T[dl * 64 + c8 * 8];
                *(uint4*)(Vrow + (size_t)(p * 32 + dl) * 1024 + c8 * 8) = val;
            }
        }
    }
}

// ---------------------------------------------------------------------------
// Attn helpers. Round-14 (T15-lite): split stage into K (2 gld) and V (2 gld);
// split chunk into QK / SM / PV so PV(i-1) [MFMA] and SM(i) [VALU] are
// independent after QK(i) and the scheduler interleaves them.
// ---------------------------------------------------------------------------
__device__ __forceinline__ void stage_K2(const unsigned short* __restrict__ Kp,
                                         int s0, unsigned short* Kd,
                                         int w, int rl, int p8) {
    #pragma unroll
    for (int cc = 0; cc < 2; ++cc) {
        const int r = 16 * w + 8 * cc + rl;
        const int jj = p8 ^ (r & 7);
        gld_lds16(Kd + (16 * w + 8 * cc) * 64, Kp + (size_t)(s0 + r) * 64 + jj * 8);
    }
}
__device__ __forceinline__ void stage_V2(const unsigned short* __restrict__ Vp,
                                         int s0, unsigned short* Vd,
                                         int w, int rl, int p8) {
    #pragma unroll
    for (int cc = 0; cc < 2; ++cc) {
        const int r = 16 * w + 8 * cc + rl;
        const int jj = p8 ^ (r & 7);
        gld_lds16(Vd + (16 * w + 8 * cc) * 64, Vp + (size_t)r * 1024 + s0 + jj * 8);
    }
}

__device__ __forceinline__ void attn_qk(const unsigned short* __restrict__ Kc,
                                        const bf16x8 (&qf)[2][2],
                                        f32x4 (&sacc)[4][2],
                                        int lo, int q4, int xr) {
    #pragma unroll
    for (int mt = 0; mt < 4; ++mt)
        #pragma unroll
        for (int nt = 0; nt < 2; ++nt)
            sacc[mt][nt] = f32x4{0.f, 0.f, 0.f, 0.f};
    __builtin_amdgcn_s_setprio(1);
    #pragma unroll
    for (int mt = 0; mt < 4; ++mt) {
        const unsigned short* kr = Kc + (16 * mt + lo) * 64;
        const bf16x8 a0 = *(const bf16x8*)(kr + ((q4    ) ^ xr) * 8);
        const bf16x8 a1 = *(const bf16x8*)(kr + ((q4 + 4) ^ xr) * 8);
        #pragma unroll
        for (int nt = 0; nt < 2; ++nt) {
            sacc[mt][nt] = __builtin_amdgcn_mfma_f32_16x16x32_bf16(a0, qf[nt][0], sacc[mt][nt], 0, 0, 0);
            sacc[mt][nt] = __builtin_amdgcn_mfma_f32_16x16x32_bf16(a1, qf[nt][1], sacc[mt][nt], 0, 0, 0);
        }
    }
    __builtin_amdgcn_s_setprio(0);
}

// P = exp2(S); pack bf16 pairs; permlane-redistribute to B-frag (verified r6-7)
__device__ __forceinline__ void attn_sm(const f32x4 (&sacc)[4][2],
                                        bf16x8 (&bp)[2][2]) {
    #pragma unroll
    for (int nt = 0; nt < 2; ++nt) {
        unsigned int X[4][2];
        #pragma unroll
        for (int mt = 0; mt < 4; ++mt) {
            const f32x4 s = sacc[mt][nt];
            const float p0 = exp2_raw(s[0]);
            const float p1 = exp2_raw(s[1]);
            const float p2 = exp2_raw(s[2]);
            const float p3 = exp2_raw(s[3]);
            X[mt][0] = pack_trunc(p0, p1);
            X[mt][1] = pack_trunc(p2, p3);
        }
        #pragma unroll
        for (int h2 = 0; h2 < 2; ++h2) {
            unsigned int Y0, Y1, Y2, Y3;
            {
                unsigned int a = X[2 * h2][0], bb = X[2 * h2 + 1][0];
                pl32_swap(a, bb);
                pl16_swap(a, bb);
                Y0 = a; Y2 = bb;
            }
            {
                unsigned int a = X[2 * h2][1], bb = X[2 * h2 + 1][1];
                pl32_swap(a, bb);
                pl16_swap(a, bb);
                Y1 = a; Y3 = bb;
            }
            union { unsigned int u[4]; bf16x8 v; } cv;
            cv.u[0] = Y0; cv.u[1] = Y1; cv.u[2] = Y2; cv.u[3] = Y3;
            bp[nt][h2] = cv.v;
        }
    }
}

// O^T += V P^T; l += 1^T P (MFMA l-sum, verified r12)
__device__ __forceinline__ void attn_pv(const unsigned short* __restrict__ Vc,
                                        const bf16x8 (&bp)[2][2],
                                        const bf16x8 ones,
                                        f32x4 (&oacc)[4][2], f32x4 (&lacc)[2],
                                        int lo, int q4, int xr) {
    __builtin_amdgcn_s_setprio(1);
    #pragma unroll
    for (int nt = 0; nt < 2; ++nt) {
        lacc[nt] = __builtin_amdgcn_mfma_f32_16x16x32_bf16(ones, bp[nt][0], lacc[nt], 0, 0, 0);
        lacc[nt] = __builtin_amdgcn_mfma_f32_16x16x32_bf16(ones, bp[nt][1], lacc[nt], 0, 0, 0);
    }
    #pragma unroll
    for (int md = 0; md < 4; ++md) {
        const unsigned short* vr = Vc + (16 * md + lo) * 64;
        const bf16x8 v0 = *(const bf16x8*)(vr + ((q4    ) ^ xr) * 8);
        const bf16x8 v1 = *(const bf16x8*)(vr + ((q4 + 4) ^ xr) * 8);
        #pragma unroll
        for (int nt = 0; nt < 2; ++nt) {
            oacc[md][nt] = __builtin_amdgcn_mfma_f32_16x16x32_bf16(v0, bp[nt][0], oacc[md][nt], 0, 0, 0);
            oacc[md][nt] = __builtin_amdgcn_mfma_f32_16x16x32_bf16(v1, bp[nt][1], oacc[md][nt], 0, 0, 0);
        }
    }
    __builtin_amdgcn_s_setprio(0);
}

// ---------------------------------------------------------------------------
// Kernel 4: MFMA flash attention. Round-14 (T15-lite): per iter i —
//   ABAR; stage_K(i+2); QK(i); PV(i-1); stage_V(i+1); SM(i)
// PV(i-1) [MFMA on prev bp] and SM(i) [VALU on fresh sacc] are independent,
// so the scheduler interleaves MFMA and VALU within the wave.
// Buffers: K 3x8KB staged 2-ahead (restage target last read iter i-1, barrier-
// separated); V 3x8KB staged 1-ahead mid-iter (restage target V(i-2), last
// read iter i-1, barrier-separated; own-wave PV reads a different buffer).
// vmcnt invariant: after barrier i in-flight = [K(i+1), V(i)] -> ABAR("4");
// K flight = 2 chunks, V flight = ~1.3 chunks. Tail: vmcnt 4/4/2/0 (traced).
// Occupancy params UNCHANGED: (256,3), 48 KB, 4 waves — the only config that
// avoids the 64-VGPR allocator bucket (rounds 5/7/9/10).
// ---------------------------------------------------------------------------
__global__ __launch_bounds__(256, 3)
void attn_mfma_kernel(const unsigned short* __restrict__ Qt,
                      const unsigned short* __restrict__ Kt,
                      const unsigned short* __restrict__ Vb,
                      unsigned short* __restrict__ attnT) {
    const int bh = blockIdx.x;
    const int b = bh >> 3, h = bh & 7;
    const int tBase = blockIdx.y * 128;
    const int tid = threadIdx.x;
    const int w = tid >> 6, lane = tid & 63;
    const int lo = lane & 15, q4 = lane >> 4;
    const int xr = lo & 7;

    __shared__ __align__(16) unsigned short Ks[3][64 * 64];    // [s][d] swizzled, 3x8 KB
    __shared__ __align__(16) unsigned short Vs[3][64 * 64];    // [d][s] swizzled, 3x8 KB

    const unsigned short* Kp = Kt + ((size_t)bh << 16);
    const unsigned short* Vp = Vb + ((size_t)b * 512 + h * 64) * 1024;

    // persistent Q B-frags: wave w owns t in [tBase+32w, +32), nt in {0,1}
    bf16x8 qf[2][2];
    {
        const unsigned short* Qp = Qt + ((size_t)bh * 1024 + tBase + 32 * w) * 64;
        #pragma unroll
        for (int nt = 0; nt < 2; ++nt) {
            qf[nt][0] = *(const bf16x8*)(Qp + (size_t)(16 * nt + lo) * 64 + 8 * q4);
            qf[nt][1] = *(const bf16x8*)(Qp + (size_t)(16 * nt + lo) * 64 + 32 + 8 * q4);
        }
    }

    // all-ones bf16 A-fragment for the l-sum contraction (1.0 = 0x3F80)
    bf16x8 ones;
    #pragma unroll
    for (int i = 0; i < 8; ++i) ones[i] = (short)0x3F80;

    const int rl = lane >> 3, p8 = lane & 7;

    f32x4 oacc[4][2] = {};
    f32x4 lacc[2] = {};
    f32x4 sacc[4][2];
    bf16x8 bp[2][2];

    // prologue: K(0), K(1), V(0) in flight (6 loads; oldest = K(0))
    stage_K2(Kp, 0 * 64, Ks[0], w, rl, p8);
    stage_K2(Kp, 1 * 64, Ks[1], w, rl, p8);
    stage_V2(Vp, 0 * 64, Vs[0], w, rl, p8);

    // iter 0: drain K(0) (leave [K1,V0]); stage K(2); QK(0); stage V(1); SM(0)
    ABAR("4");
    stage_K2(Kp, 2 * 64, Ks[2], w, rl, p8);
    attn_qk(Ks[0], qf, sacc, lo, q4, xr);
    stage_V2(Vp, 1 * 64, Vs[1], w, rl, p8);
    attn_sm(sacc, bp);

    // iters 1..12 (3-periodic, compile-time buffers)
    #pragma unroll 1
    for (int ii = 0; ii < 4; ++ii) {
        const int i = 3 * ii + 1;
        // iter i (i%3==1): K read Ks[1], K(i+2)->Ks[0], PV V Vs[0], V(i+1)->Vs[2]
        ABAR("4");
        stage_K2(Kp, (i + 2) * 64, Ks[0], w, rl, p8);
        attn_qk(Ks[1], qf, sacc, lo, q4, xr);
        attn_pv(Vs[0], bp, ones, oacc, lacc, lo, q4, xr);
        stage_V2(Vp, (i + 1) * 64, Vs[2], w, rl, p8);
        attn_sm(sacc, bp);
        // iter i+1 (%3==2): K read Ks[2], K->Ks[1], PV Vs[1], V->Vs[0]
        ABAR("4");
        stage_K2(Kp, (i + 3) * 64, Ks[1], w, rl, p8);
        attn_qk(Ks[2], qf, sacc, lo, q4, xr);
        attn_pv(Vs[1], bp, ones, oacc, lacc, lo, q4, xr);
        stage_V2(Vp, (i + 2) * 64, Vs[0], w, rl, p8);
        attn_sm(sacc, bp);
        // iter i+2 (%3==0): K read Ks[0], K->Ks[2], PV Vs[2], V->Vs[1]
        ABAR("4");
        stage_K2(Kp, (i + 4) * 64, Ks[2], w, rl, p8);
        attn_qk(Ks[0], qf, sacc, lo, q4, xr);
        attn_pv(Vs[2], bp, ones, oacc, lacc, lo, q4, xr);
        stage_V2(Vp, (i + 3) * 64, Vs[1], w, rl, p8);
        attn_sm(sacc, bp);
    }

    // iter 13 (%3==1): last K stage (K15); PV(12) Vs[0]; V(14)->Vs[2]
    ABAR("4");
    stage_K2(Kp, 15 * 64, Ks[0], w, rl, p8);
    attn_qk(Ks[1], qf, sacc, lo, q4, xr);
    attn_pv(Vs[0], bp, ones, oacc, lacc, lo, q4, xr);
    stage_V2(Vp, 14 * 64, Vs[2], w, rl, p8);
    attn_sm(sacc, bp);
    // iter 14 (%3==2): no K stage; PV(13) Vs[1]; V(15)->Vs[0]
    ABAR("4");
    attn_qk(Ks[2], qf, sacc, lo, q4, xr);
    attn_pv(Vs[1], bp, ones, oacc, lacc, lo, q4, xr);
    stage_V2(Vp, 15 * 64, Vs[0], w, rl, p8);
    attn_sm(sacc, bp);
    // iter 15 (%3==0): drain K(15),V(14) (leave V(15)); QK(15); PV(14) Vs[2]
    ABAR("2");
    attn_qk(Ks[0], qf, sacc, lo, q4, xr);
    attn_pv(Vs[2], bp, ones, oacc, lacc, lo, q4, xr);
    attn_sm(sacc, bp);
    // final: drain V(15), barrier, PV(15) from Vs[0]
    ABAR("0");
    attn_pv(Vs[0], bp, ones, oacc, lacc, lo, q4, xr);

    // ---- epilogue: l[t] complete in lacc[nt][0]; no cross-lane reduce.
    #pragma unroll
    for (int nt = 0; nt < 2; ++nt) {
        const float inv = 1.0f / lacc[nt][0];
        const int t = tBase + 32 * w + 16 * nt + lo;
        unsigned short* op = attnT + ((size_t)(b * 1024 + t)) * 512 + h * 64;
        #pragma unroll
        for (int md = 0; md < 4; ++md) {
            uint2 pk;
            pk.x = pack_trunc(oacc[md][nt][0] * inv, oacc[md][nt][1] * inv);
            pk.y = pack_trunc(oacc[md][nt][2] * inv, oacc[md][nt][3] * inv);
            *(uint2*)(op + 16 * md + 4 * q4) = pk;
        }
    }
}

// ---------------------------------------------------------------------------
// Kernel 5: proj GEMM + bias + residual. 1D grid + bijective XCD remap.
// ---------------------------------------------------------------------------
__global__ __launch_bounds__(256)
void proj_mfma_kernel(const unsigned short* __restrict__ wpb,
                      const unsigned short* __restrict__ attnT,
                      const float* __restrict__ proj_b,
                      const float* __restrict__ x,
                      float* __restrict__ out) {
    __shared__ __align__(16) unsigned short SMEM[3 * 8192];  // 48 KB pipeline
    const int hw_id = blockIdx.x;
    const int wk = (hw_id % 64) * 8 + hw_id / 64;     // bijective, 512 = 8*64
    const int bx = wk & 7;            // nBase index
    const int by = (wk >> 3) & 3;     // mBase index
    const int batch = wk >> 5;
    const int mBase = by * 128, nBase = bx * 128;

    f32x4 acc[4][4] = {};
    mfma_gemm_pipe((const char*)(wpb + (size_t)mBase * 512),
                   (const char*)(attnT + ((size_t)batch * 1024 + nBase) * 512),
                   SMEM, acc);

    const int tid = threadIdx.x;
    const int w = tid >> 6, lane = tid & 63;
    const int lo = lane & 15, q4 = lane >> 4;
    const int wm = w >> 1, wn = w & 1;
    const float* xb = x + (size_t)batch * 524288;
    float* ob = out + (size_t)batch * 524288;

    #pragma unroll
    for (int mi = 0; mi < 4; ++mi) {
        const int m0 = mBase + wm * 64 + mi * 16 + q4 * 4;
        const float4 bq = *(const float4*)(proj_b + m0);
        #pragma unroll
        for (int ni = 0; ni < 4; ++ni) {
            const int t = nBase + wn * 64 + ni * 16 + lo;
            const size_t o0 = (size_t)m0 * 1024 + t;
            ob[o0]          = acc[mi][ni][0] + bq.x + xb[o0];
            ob[o0 + 1024]   = acc[mi][ni][1] + bq.y + xb[o0 + 1024];
            ob[o0 + 2048]   = acc[mi][ni][2] + bq.z + xb[o0 + 2048];
            ob[o0 + 3072]   = acc[mi][ni][3] + bq.w + xb[o0 + 3072];
        }
    }
}

// ---------------------------------------------------------------------------
// Launch
// ---------------------------------------------------------------------------
extern "C" void kernel_launch(void* const* d_in, const int* in_sizes, int n_in,
                              void* d_out, int out_size, void* d_ws, size_t ws_size,
                              hipStream_t stream) {
    const float* x        = (const float*)d_in[0];
    const float* gn_gamma = (const float*)d_in[1];
    const float* gn_beta  = (const float*)d_in[2];
    const float* qkv_w    = (const float*)d_in[3];
    const float* qkv_b    = (const float*)d_in[4];
    const float* proj_w   = (const float*)d_in[5];
    const float* proj_b   = (const float*)d_in[6];
    float* out = (float*)d_out;

    // workspace layout (~86 MiB)
    char* wsc = (char*)d_ws;
    unsigned short* xnT   = (unsigned short*)(wsc);              // 16 MiB [b][t][c]
    unsigned short* Qt    = (unsigned short*)(wsc + 16777216);   // 16 MiB [bh][t][d]
    unsigned short* Kt    = (unsigned short*)(wsc + 33554432);   // 16 MiB [bh][t][d]
    unsigned short* Vb    = (unsigned short*)(wsc + 50331648);   // 16 MiB [b][d'][t]
    unsigned short* attnT = (unsigned short*)(wsc + 67108864);   // 16 MiB [b][t][c]
    unsigned short* wqb   = (unsigned short*)(wsc + 83886080);   // 1.5 MiB (wpb follows)
    unsigned short* wpb   = wqb + 786432;                        // 0.5 MiB

    // 1. GroupNorm + weight conversion (fused, independent block ranges)
    fused_pre_kernel<<<1536, 256, 0, stream>>>(x, gn_gamma, gn_beta, xnT,
                                               qkv_w, proj_w, wqb);

    // 2. QKV MFMA GEMM (writes Qt, Kt, Vb directly), XCD-swizzled 1D grid
    qkv_mfma_kernel<<<1536, 256, 0, stream>>>(wqb, xnT, qkv_b, Qt, Kt, Vb);

    // 3. MFMA flash attention -> attnT bf16 (128 queries/block, 1024 blocks)
    {
        dim3 grid(B * NUM_HEADS, HW / 128);
        attn_mfma_kernel<<<grid, 256, 0, stream>>>(Qt, Kt, Vb, attnT);
    }

    // 4. Proj MFMA GEMM + bias + residual -> fp32 out, XCD-swizzled 1D grid
    proj_mfma_kernel<<<512, 256, 0, stream>>>(wpb, attnT, proj_b, x, out);
}